// Round 5
// baseline (76.811 us; speedup 1.0000x reference)
//
#include <hip/hip_runtime.h>
#include <math.h>

#define BB 16
#define NN 256
#define DD 32
#define RG 8               // rows per block
#define BPB (NN / RG)      // blocks per batch = 32

// Single fused kernel (plus a 64B memsetAsync for the arrival counters).
// Block = (b, rowgroup of 8 rows), 512 blocks x 256 threads, 2 blocks/CU
// guaranteed co-resident (34KB LDS, VGPR capped by __launch_bounds__(256,2)).
//
// Phase 0: stage x[b] (32KB) into LDS, coalesced, float4-granule XOR swizzle.
// Phase 1: thread t computes its column's u_t = x_t @ W_out[0:32] in regs
//          (redundant per block; replaces a separate kernel + global trip);
//          threads cooperatively compute the block's 8 rows of
//          v_i = x_i @ W_out[32:64] + b_out into LDS.
// Phase 2: pair loop over 8 rows; m kept in registers; per-row sum/sumsq via
//          deterministic wave shuffle tree -> rowsum/rowsq in global.
// Phase 3: per-batch spin barrier (release atomicAdd + acquire spin on
//          counter[b], agent scope -> cross-XCD safe). Then batch stats via
//            sum(m2) = 2*sum(m);  sum(m2^2) = sum(m^2) + 3*N*sum_i(rowmean^2)
//          normalize registers, one coalesced store to out.
__global__ __launch_bounds__(256, 2) void fused_kernel(
    const float* __restrict__ x,
    const float* __restrict__ W_out, const float* __restrict__ b_out,
    const float* __restrict__ W_cat, const float* __restrict__ b_cat,
    const float* __restrict__ W_f1,  const float* __restrict__ b_f1,
    const float* __restrict__ W_f2,  const float* __restrict__ b_f2,
    int* __restrict__ counter,
    float* __restrict__ rowsum, float* __restrict__ rowsq,
    float* __restrict__ out)
{
    __shared__ float4 lx4[NN * 8];              // 32KB swizzled x[b]
    __shared__ float  lv[RG][DD];               // 1KB rows' v
    __shared__ float  red0[RG][4], red1[RG][4];
    __shared__ float  lrow[RG];                 // final row sums
    __shared__ float  sred[12], stat[2];

    const int t  = threadIdx.x;
    const int b  = blockIdx.x >> 5;
    const int i0 = (blockIdx.x & 31) * RG;

    // ---- Phase 0: stage x[b] ----
    const float4* xb4 = (const float4*)(x + (size_t)b * NN * DD);
#pragma unroll
    for (int k = 0; k < 8; ++k) {
        int f = k * 256 + t;                    // 2048 float4s
        int n = f >> 3, c = f & 7;
        lx4[n * 8 + (c ^ (n & 7))] = xb4[f];
    }
    __syncthreads();

    // ---- Phase 1a: my column x_t -> regs ----
    float xj[DD];
#pragma unroll
    for (int c = 0; c < 8; ++c) {
        float4 xx = lx4[t * 8 + (c ^ (t & 7))];
        xj[4*c+0] = xx.x; xj[4*c+1] = xx.y; xj[4*c+2] = xx.z; xj[4*c+3] = xx.w;
    }
    // u_t = x_t @ W_top  (W reads are wave-uniform -> scalar loads)
    float u[DD];
#pragma unroll
    for (int d = 0; d < DD; ++d) u[d] = 0.f;
#pragma unroll
    for (int k = 0; k < DD; ++k) {
        float xv = xj[k];
#pragma unroll
        for (int d = 0; d < DD; ++d)
            u[d] += xv * W_out[k * DD + d];
    }
    // ---- Phase 1b: v for my block's 8 rows (thread = (row, dim)) ----
    {
        int r = t >> 5, d = t & 31;
        int i = i0 + r;
        const float* lxf = (const float*)lx4;
        float sv = 0.f;
#pragma unroll
        for (int k = 0; k < DD; ++k) {
            float xv = lxf[(i * 8 + ((k >> 2) ^ (i & 7))) * 4 + (k & 3)];
            sv += xv * W_out[(k + DD) * DD + d];
        }
        lv[r][d] = sv + b_out[d];
    }
    // small weights (wave-uniform -> SGPRs)
    float wcv[DD];
#pragma unroll
    for (int d = 0; d < DD; ++d) wcv[d] = W_cat[d];
    float f1a[8], f1b[8], fb1[8], f2w[8];
#pragma unroll
    for (int k = 0; k < 8; ++k) {
        f1a[k] = W_f1[k];        // W_f1[0,k]
        f1b[k] = W_f1[8 + k];    // W_f1[1,k]
        fb1[k] = b_f1[k];
        f2w[k] = W_f2[k];
    }
    const float bcat = b_cat[0], bf2 = b_f2[0];
    __syncthreads();

    // ---- Phase 2: pairs ----
    const int lane = t & 63, wv = t >> 6;
    const float4* lvv4 = (const float4*)lv;
    float mreg[RG];
#pragma unroll
    for (int r = 0; r < RG; ++r) {
        int i = i0 + r;
        float e = 0.f, mp = 0.f;
#pragma unroll
        for (int q = 0; q < 8; ++q) {
            float4 vi = lvv4[r * 8 + q];              // broadcast
            float4 xi = lx4[i * 8 + (q ^ (i & 7))];   // broadcast
            e += fmaxf(u[4*q+0] + vi.x, 0.f) * wcv[4*q+0];
            e += fmaxf(u[4*q+1] + vi.y, 0.f) * wcv[4*q+1];
            e += fmaxf(u[4*q+2] + vi.z, 0.f) * wcv[4*q+2];
            e += fmaxf(u[4*q+3] + vi.w, 0.f) * wcv[4*q+3];
            mp += xj[4*q+0]*xi.x + xj[4*q+1]*xi.y + xj[4*q+2]*xi.z + xj[4*q+3]*xi.w;
        }
        e = fmaxf(e + bcat, 0.f);
        float mlin = (t == i) ? 0.f : e;
        float s = bf2;
#pragma unroll
        for (int k = 0; k < 8; ++k)
            s += fmaxf(mlin * f1a[k] + mp * f1b[k] + fb1[k], 0.f) * f2w[k];
        float w = 1.f / (1.f + expf(-s));
        float m = w * mlin + (1.f - w) * mp;
        mreg[r] = m;

        float sm = m, sq = m * m;                 // deterministic tree
#pragma unroll
        for (int off = 32; off; off >>= 1) {
            sm += __shfl_down(sm, off);
            sq += __shfl_down(sq, off);
        }
        if (lane == 0) { red0[r][wv] = sm; red1[r][wv] = sq; }
    }
    __syncthreads();
    if (t < RG) {
        float rs = red0[t][0] + red0[t][1] + red0[t][2] + red0[t][3];
        float rq = red1[t][0] + red1[t][1] + red1[t][2] + red1[t][3];
        lrow[t] = rs;
        rowsum[b * NN + i0 + t] = rs;
        rowsq [b * NN + i0 + t] = rq;
    }

    // ---- Phase 3: per-batch barrier ----
    __threadfence();                              // publish rowsum/rowsq
    if (t == 0) {
        __hip_atomic_fetch_add(&counter[b], 1, __ATOMIC_RELEASE,
                               __HIP_MEMORY_SCOPE_AGENT);
        long guard = 0;
        while (__hip_atomic_load(&counter[b], __ATOMIC_ACQUIRE,
                                 __HIP_MEMORY_SCOPE_AGENT) < BPB) {
            __builtin_amdgcn_s_sleep(2);
            if (++guard > (1L << 26)) break;      // anti-hang insurance
        }
    }
    __syncthreads();

    // batch stats from 256 rowsum/rowsq (agent-scope loads: bypass stale L1)
    {
        float rs = __hip_atomic_load(&rowsum[b * NN + t], __ATOMIC_RELAXED,
                                     __HIP_MEMORY_SCOPE_AGENT);
        float rq = __hip_atomic_load(&rowsq[b * NN + t], __ATOMIC_RELAXED,
                                     __HIP_MEMORY_SCOPE_AGENT);
        float rr = rs * (1.f / NN);
        float sM = rs, sQ = rq, sR = rr * rr;
#pragma unroll
        for (int off = 32; off; off >>= 1) {
            sM += __shfl_down(sM, off);
            sQ += __shfl_down(sQ, off);
            sR += __shfl_down(sR, off);
        }
        if (lane == 0) { sred[wv] = sM; sred[4 + wv] = sQ; sred[8 + wv] = sR; }
        __syncthreads();
        if (t == 0) {
            float sumM  = sred[0] + sred[1] + sred[2] + sred[3];
            float sumQ  = sred[4] + sred[5] + sred[6] + sred[7];
            float sumR2 = sred[8] + sred[9] + sred[10] + sred[11];
            const float inv = 1.f / ((float)NN * (float)NN);
            float mu  = 2.f * sumM * inv;
            float ex2 = (sumQ + 3.f * (float)NN * sumR2) * inv;
            stat[0] = mu;
            stat[1] = rsqrtf(ex2 - mu * mu + 1e-5f);
        }
        __syncthreads();
    }
    float mu = stat[0], rstd = stat[1];
#pragma unroll
    for (int r = 0; r < RG; ++r) {
        float ri = lrow[r] * (1.f / NN);
        out[((size_t)b * NN + i0 + r) * NN + t] = (mreg[r] + ri - mu) * rstd;
    }
}

extern "C" void kernel_launch(void* const* d_in, const int* in_sizes, int n_in,
                              void* d_out, int out_size, void* d_ws, size_t ws_size,
                              hipStream_t stream)
{
    const float* x     = (const float*)d_in[0];
    const float* W_out = (const float*)d_in[1];
    const float* b_out = (const float*)d_in[2];
    const float* W_cat = (const float*)d_in[3];
    const float* b_cat = (const float*)d_in[4];
    const float* W_f1  = (const float*)d_in[5];
    const float* b_f1  = (const float*)d_in[6];
    const float* W_f2  = (const float*)d_in[7];
    const float* b_f2  = (const float*)d_in[8];

    int*   counter = (int*)d_ws;                          // 16 ints (64 B)
    float* rowsum  = (float*)((char*)d_ws + 64);          // BB*NN
    float* rowsq   = rowsum + BB * NN;                    // BB*NN
    float* outp    = (float*)d_out;

    hipMemsetAsync(counter, 0, BB * sizeof(int), stream);
    fused_kernel<<<BB * BPB, 256, 0, stream>>>(
        x, W_out, b_out, W_cat, b_cat, W_f1, b_f1, W_f2, b_f2,
        counter, rowsum, rowsq, outp);
}

// Round 6
// 74.345 us; speedup vs baseline: 1.0332x; 1.0332x over previous
//
#include <hip/hip_runtime.h>
#include <math.h>

#define BB 16
#define NN 256
#define DD 32
#define RG 8               // rows per block
#define BPB (NN / RG)      // blocks per batch = 32

// Single fused kernel (plus 64B memsetAsync for arrival counters).
// Block = (b, rowgroup of 8 rows): 512 blocks x 256 threads = 2 blocks/CU
// co-resident (33KB LDS). amdgpu_waves_per_eu(2,2) pins the allocator's
// occupancy target at 2 waves/EU -> 256-VGPR budget -> no scratch spills
// (round-5 showed VGPR_Count=60 with ~100 live floats = massive spill).
//
// Phase 0: stage x[b] (32KB) into LDS, coalesced, float4-granule XOR swizzle.
// Phase 1: thread t computes its own column's u_t = x_t @ W_out[0:32] in regs
//          (4 passes x 8 accumulators to bound peak pressure); threads
//          cooperatively compute the block's 8 rows of
//          v_i = x_i @ W_out[32:64] + b_out into LDS (coalesced W loads).
// Phase 2: pair loop over 8 rows; m kept in registers; per-row sum/sumsq via
//          deterministic wave shuffle tree -> rowsum/rowsq in global.
// Phase 3: per-batch spin barrier (release atomicAdd + acquire spin, agent
//          scope -> cross-XCD safe per G16). Batch stats via
//            sum(m2) = 2*sum(m);  sum(m2^2) = sum(m^2) + 3*N*sum_i(rowmean^2)
//          then normalize registers, one coalesced store.
__attribute__((amdgpu_flat_work_group_size(256, 256), amdgpu_waves_per_eu(2, 2)))
__global__ void fused_kernel(
    const float* __restrict__ x,
    const float* __restrict__ W_out, const float* __restrict__ b_out,
    const float* __restrict__ W_cat, const float* __restrict__ b_cat,
    const float* __restrict__ W_f1,  const float* __restrict__ b_f1,
    const float* __restrict__ W_f2,  const float* __restrict__ b_f2,
    int* __restrict__ counter,
    float* __restrict__ rowsum, float* __restrict__ rowsq,
    float* __restrict__ out)
{
    __shared__ float4 lx4[NN * 8];              // 32KB swizzled x[b]
    __shared__ float4 lv4[RG * 8];              // 512B rows' v (float4-aligned)
    __shared__ float  red0[RG][4], red1[RG][4];
    __shared__ float  lrow[RG];                 // final row sums
    __shared__ float  sred[12], stat[2];

    const int t  = threadIdx.x;
    const int b  = blockIdx.x >> 5;
    const int i0 = (blockIdx.x & 31) * RG;

    // ---- Phase 0: stage x[b], swizzled ----
    const float4* xb4 = (const float4*)(x + (size_t)b * NN * DD);
#pragma unroll
    for (int k = 0; k < 8; ++k) {
        int f = k * 256 + t;                    // 2048 float4s
        int n = f >> 3, c = f & 7;
        lx4[n * 8 + (c ^ (n & 7))] = xb4[f];
    }
    __syncthreads();

    // ---- Phase 1a: my column x_t -> regs ----
    float xj[DD];
#pragma unroll
    for (int c = 0; c < 8; ++c) {
        float4 xx = lx4[t * 8 + (c ^ (t & 7))];
        xj[4*c+0] = xx.x; xj[4*c+1] = xx.y; xj[4*c+2] = xx.z; xj[4*c+3] = xx.w;
    }

    // ---- Phase 1b: u_t = x_t @ W_top, 4 passes x 8 accumulators ----
    float u[DD];
#pragma unroll
    for (int p = 0; p < 4; ++p) {
        float acc[8];
#pragma unroll
        for (int j8 = 0; j8 < 8; ++j8) acc[j8] = 0.f;
#pragma unroll
        for (int k = 0; k < DD; ++k) {
            float xv = xj[k];
#pragma unroll
            for (int j8 = 0; j8 < 8; ++j8)
                acc[j8] += xv * W_out[k * DD + p * 8 + j8];   // uniform -> s_load
        }
#pragma unroll
        for (int j8 = 0; j8 < 8; ++j8) u[p * 8 + j8] = acc[j8];
    }

    // ---- Phase 1c: v for my block's 8 rows (thread = (row, dim)) ----
    {
        int r = t >> 5, d = t & 31;
        int i = i0 + r;
        const float* lxf = (const float*)lx4;
        float sv = 0.f;
#pragma unroll
        for (int k = 0; k < DD; ++k) {
            float xv = lxf[(i * 8 + ((k >> 2) ^ (i & 7))) * 4 + (k & 3)];
            sv += xv * W_out[(k + DD) * DD + d];              // coalesced vector
        }
        ((float*)lv4)[r * DD + d] = sv + b_out[d];
    }

    // small weights (wave-uniform -> scalar regs)
    float wcv[DD];
#pragma unroll
    for (int d = 0; d < DD; ++d) wcv[d] = W_cat[d];
    float f1a[8], f1b[8], fb1[8], f2w[8];
#pragma unroll
    for (int k = 0; k < 8; ++k) {
        f1a[k] = W_f1[k];        // W_f1[0,k]
        f1b[k] = W_f1[8 + k];    // W_f1[1,k]
        fb1[k] = b_f1[k];
        f2w[k] = W_f2[k];
    }
    const float bcat = b_cat[0], bf2 = b_f2[0];
    __syncthreads();

    // ---- Phase 2: pairs ----
    const int lane = t & 63, wv = t >> 6;
    float mreg[RG];
#pragma unroll
    for (int r = 0; r < RG; ++r) {
        int i = i0 + r;
        float e = 0.f, mp = 0.f;
#pragma unroll
        for (int q = 0; q < 8; ++q) {
            float4 vi = lv4[r * 8 + q];               // broadcast
            float4 xi = lx4[i * 8 + (q ^ (i & 7))];   // broadcast
            e += fmaxf(u[4*q+0] + vi.x, 0.f) * wcv[4*q+0];
            e += fmaxf(u[4*q+1] + vi.y, 0.f) * wcv[4*q+1];
            e += fmaxf(u[4*q+2] + vi.z, 0.f) * wcv[4*q+2];
            e += fmaxf(u[4*q+3] + vi.w, 0.f) * wcv[4*q+3];
            mp += xj[4*q+0]*xi.x + xj[4*q+1]*xi.y + xj[4*q+2]*xi.z + xj[4*q+3]*xi.w;
        }
        e = fmaxf(e + bcat, 0.f);
        float mlin = (t == i) ? 0.f : e;
        float s = bf2;
#pragma unroll
        for (int k = 0; k < 8; ++k)
            s += fmaxf(mlin * f1a[k] + mp * f1b[k] + fb1[k], 0.f) * f2w[k];
        float w = 1.f / (1.f + expf(-s));
        float m = w * mlin + (1.f - w) * mp;
        mreg[r] = m;

        float sm = m, sq = m * m;                 // deterministic tree
#pragma unroll
        for (int off = 32; off; off >>= 1) {
            sm += __shfl_down(sm, off);
            sq += __shfl_down(sq, off);
        }
        if (lane == 0) { red0[r][wv] = sm; red1[r][wv] = sq; }
    }
    __syncthreads();
    if (t < RG) {
        float rs = red0[t][0] + red0[t][1] + red0[t][2] + red0[t][3];
        float rq = red1[t][0] + red1[t][1] + red1[t][2] + red1[t][3];
        lrow[t] = rs;
        rowsum[b * NN + i0 + t] = rs;
        rowsq [b * NN + i0 + t] = rq;
    }

    // ---- Phase 3: per-batch spin barrier ----
    __threadfence();                              // publish rowsum/rowsq
    if (t == 0) {
        __hip_atomic_fetch_add(&counter[b], 1, __ATOMIC_RELEASE,
                               __HIP_MEMORY_SCOPE_AGENT);
        long guard = 0;
        while (__hip_atomic_load(&counter[b], __ATOMIC_ACQUIRE,
                                 __HIP_MEMORY_SCOPE_AGENT) < BPB) {
            __builtin_amdgcn_s_sleep(2);
            if (++guard > (1L << 26)) break;      // anti-hang insurance
        }
    }
    __syncthreads();

    // batch stats from 256 rowsum/rowsq (agent-scope loads bypass stale L1)
    {
        float rs = __hip_atomic_load(&rowsum[b * NN + t], __ATOMIC_RELAXED,
                                     __HIP_MEMORY_SCOPE_AGENT);
        float rq = __hip_atomic_load(&rowsq[b * NN + t], __ATOMIC_RELAXED,
                                     __HIP_MEMORY_SCOPE_AGENT);
        float rr = rs * (1.f / NN);
        float sM = rs, sQ = rq, sR = rr * rr;
#pragma unroll
        for (int off = 32; off; off >>= 1) {
            sM += __shfl_down(sM, off);
            sQ += __shfl_down(sQ, off);
            sR += __shfl_down(sR, off);
        }
        if (lane == 0) { sred[wv] = sM; sred[4 + wv] = sQ; sred[8 + wv] = sR; }
        __syncthreads();
        if (t == 0) {
            float sumM  = sred[0] + sred[1] + sred[2] + sred[3];
            float sumQ  = sred[4] + sred[5] + sred[6] + sred[7];
            float sumR2 = sred[8] + sred[9] + sred[10] + sred[11];
            const float inv = 1.f / ((float)NN * (float)NN);
            float mu  = 2.f * sumM * inv;
            float ex2 = (sumQ + 3.f * (float)NN * sumR2) * inv;
            stat[0] = mu;
            stat[1] = rsqrtf(ex2 - mu * mu + 1e-5f);
        }
        __syncthreads();
    }
    float mu = stat[0], rstd = stat[1];
#pragma unroll
    for (int r = 0; r < RG; ++r) {
        float ri = lrow[r] * (1.f / NN);
        out[((size_t)b * NN + i0 + r) * NN + t] = (mreg[r] + ri - mu) * rstd;
    }
}

extern "C" void kernel_launch(void* const* d_in, const int* in_sizes, int n_in,
                              void* d_out, int out_size, void* d_ws, size_t ws_size,
                              hipStream_t stream)
{
    const float* x     = (const float*)d_in[0];
    const float* W_out = (const float*)d_in[1];
    const float* b_out = (const float*)d_in[2];
    const float* W_cat = (const float*)d_in[3];
    const float* b_cat = (const float*)d_in[4];
    const float* W_f1  = (const float*)d_in[5];
    const float* b_f1  = (const float*)d_in[6];
    const float* W_f2  = (const float*)d_in[7];
    const float* b_f2  = (const float*)d_in[8];

    int*   counter = (int*)d_ws;                          // 16 ints (64 B)
    float* rowsum  = (float*)((char*)d_ws + 64);          // BB*NN
    float* rowsq   = rowsum + BB * NN;                    // BB*NN
    float* outp    = (float*)d_out;

    hipMemsetAsync(counter, 0, BB * sizeof(int), stream);
    fused_kernel<<<BB * BPB, 256, 0, stream>>>(
        x, W_out, b_out, W_cat, b_cat, W_f1, b_f1, W_f2, b_f2,
        counter, rowsum, rowsq, outp);
}

// Round 7
// 22.422 us; speedup vs baseline: 3.4257x; 3.3157x over previous
//
#include <hip/hip_runtime.h>
#include <math.h>

#define BB 16
#define NN 256
#define DD 32
#define RG 8               // rows per block
#define BPB (NN / RG)      // blocks per batch = 32

// Two-kernel A/B ablation of round-6's fused kernel: identical compute body,
// spin-barrier/threadfence/atomics removed. Split at the batch-stats sync:
//   K_pair : everything up to m (written to d_out) + rowsum/rowsq (ws)
//   K_final: redundant per-block batch stats + in-place normalize of d_out
// Both grids are 512 blocks x 256 threads (2 blocks/CU), identical
// blockIdx->rowgroup mapping, so K_final re-reads the m it wrote on the same
// XCD (L2-local).
__attribute__((amdgpu_flat_work_group_size(256, 256), amdgpu_waves_per_eu(2, 2)))
__global__ void pair_kernel(
    const float* __restrict__ x,
    const float* __restrict__ W_out, const float* __restrict__ b_out,
    const float* __restrict__ W_cat, const float* __restrict__ b_cat,
    const float* __restrict__ W_f1,  const float* __restrict__ b_f1,
    const float* __restrict__ W_f2,  const float* __restrict__ b_f2,
    float* __restrict__ rowsum, float* __restrict__ rowsq,
    float* __restrict__ out)
{
    __shared__ float4 lx4[NN * 8];              // 32KB swizzled x[b]
    __shared__ float4 lv4[RG * 8];              // 512B rows' v
    __shared__ float  red0[RG][4], red1[RG][4];

    const int t  = threadIdx.x;
    const int b  = blockIdx.x >> 5;
    const int i0 = (blockIdx.x & 31) * RG;

    // ---- Phase 0: stage x[b], swizzled ----
    const float4* xb4 = (const float4*)(x + (size_t)b * NN * DD);
#pragma unroll
    for (int k = 0; k < 8; ++k) {
        int f = k * 256 + t;                    // 2048 float4s
        int n = f >> 3, c = f & 7;
        lx4[n * 8 + (c ^ (n & 7))] = xb4[f];
    }
    __syncthreads();

    // ---- Phase 1a: my column x_t -> regs ----
    float xj[DD];
#pragma unroll
    for (int c = 0; c < 8; ++c) {
        float4 xx = lx4[t * 8 + (c ^ (t & 7))];
        xj[4*c+0] = xx.x; xj[4*c+1] = xx.y; xj[4*c+2] = xx.z; xj[4*c+3] = xx.w;
    }

    // ---- Phase 1b: u_t = x_t @ W_top, 4 passes x 8 accumulators ----
    float u[DD];
#pragma unroll
    for (int p = 0; p < 4; ++p) {
        float acc[8];
#pragma unroll
        for (int j8 = 0; j8 < 8; ++j8) acc[j8] = 0.f;
#pragma unroll
        for (int k = 0; k < DD; ++k) {
            float xv = xj[k];
#pragma unroll
            for (int j8 = 0; j8 < 8; ++j8)
                acc[j8] += xv * W_out[k * DD + p * 8 + j8];   // uniform -> s_load
        }
#pragma unroll
        for (int j8 = 0; j8 < 8; ++j8) u[p * 8 + j8] = acc[j8];
    }

    // ---- Phase 1c: v for my block's 8 rows (thread = (row, dim)) ----
    {
        int r = t >> 5, d = t & 31;
        int i = i0 + r;
        const float* lxf = (const float*)lx4;
        float sv = 0.f;
#pragma unroll
        for (int k = 0; k < DD; ++k) {
            float xv = lxf[(i * 8 + ((k >> 2) ^ (i & 7))) * 4 + (k & 3)];
            sv += xv * W_out[(k + DD) * DD + d];              // coalesced vector
        }
        ((float*)lv4)[r * DD + d] = sv + b_out[d];
    }

    // small weights (wave-uniform -> scalar regs)
    float wcv[DD];
#pragma unroll
    for (int d = 0; d < DD; ++d) wcv[d] = W_cat[d];
    float f1a[8], f1b[8], fb1[8], f2w[8];
#pragma unroll
    for (int k = 0; k < 8; ++k) {
        f1a[k] = W_f1[k];        // W_f1[0,k]
        f1b[k] = W_f1[8 + k];    // W_f1[1,k]
        fb1[k] = b_f1[k];
        f2w[k] = W_f2[k];
    }
    const float bcat = b_cat[0], bf2 = b_f2[0];
    __syncthreads();

    // ---- Phase 2: pairs ----
    const int lane = t & 63, wv = t >> 6;
#pragma unroll
    for (int r = 0; r < RG; ++r) {
        int i = i0 + r;
        float e = 0.f, mp = 0.f;
#pragma unroll
        for (int q = 0; q < 8; ++q) {
            float4 vi = lv4[r * 8 + q];               // broadcast
            float4 xi = lx4[i * 8 + (q ^ (i & 7))];   // broadcast
            e += fmaxf(u[4*q+0] + vi.x, 0.f) * wcv[4*q+0];
            e += fmaxf(u[4*q+1] + vi.y, 0.f) * wcv[4*q+1];
            e += fmaxf(u[4*q+2] + vi.z, 0.f) * wcv[4*q+2];
            e += fmaxf(u[4*q+3] + vi.w, 0.f) * wcv[4*q+3];
            mp += xj[4*q+0]*xi.x + xj[4*q+1]*xi.y + xj[4*q+2]*xi.z + xj[4*q+3]*xi.w;
        }
        e = fmaxf(e + bcat, 0.f);
        float mlin = (t == i) ? 0.f : e;
        float s = bf2;
#pragma unroll
        for (int k = 0; k < 8; ++k)
            s += fmaxf(mlin * f1a[k] + mp * f1b[k] + fb1[k], 0.f) * f2w[k];
        float w = 1.f / (1.f + expf(-s));
        float m = w * mlin + (1.f - w) * mp;

        out[((size_t)b * NN + i) * NN + t] = m;   // coalesced store (pre-norm)

        float sm = m, sq = m * m;                 // deterministic tree
#pragma unroll
        for (int off = 32; off; off >>= 1) {
            sm += __shfl_down(sm, off);
            sq += __shfl_down(sq, off);
        }
        if (lane == 0) { red0[r][wv] = sm; red1[r][wv] = sq; }
    }
    __syncthreads();
    if (t < RG) {
        rowsum[b * NN + i0 + t] = red0[t][0] + red0[t][1] + red0[t][2] + red0[t][3];
        rowsq [b * NN + i0 + t] = red1[t][0] + red1[t][1] + red1[t][2] + red1[t][3];
    }
}

// K_final: redundant per-block batch stats (2KB rowsum/rowsq, L2-hot) via
//   sum(m2) = 2*sum(m);  sum(m2^2) = sum(m^2) + 3*N*sum_i(rowmean_i^2)
// then in-place: out[b,i,j] = (out[b,i,j] + rowmean_i - mu) * rstd.
__global__ __launch_bounds__(256) void final_kernel(
    const float* __restrict__ rowsum, const float* __restrict__ rowsq,
    float* __restrict__ out)
{
    __shared__ float sred[12];
    __shared__ float stat[2];
    const int t  = threadIdx.x;
    const int b  = blockIdx.x >> 5;
    const int i0 = (blockIdx.x & 31) * RG;

    float rs = rowsum[b * NN + t];
    float rq = rowsq [b * NN + t];
    float rr = rs * (1.f / NN);
    float sM = rs, sQ = rq, sR = rr * rr;
#pragma unroll
    for (int off = 32; off; off >>= 1) {
        sM += __shfl_down(sM, off);
        sQ += __shfl_down(sQ, off);
        sR += __shfl_down(sR, off);
    }
    const int wave = t >> 6;
    if ((t & 63) == 0) { sred[wave] = sM; sred[4 + wave] = sQ; sred[8 + wave] = sR; }
    __syncthreads();
    if (t == 0) {
        float sumM  = sred[0] + sred[1] + sred[2] + sred[3];
        float sumQ  = sred[4] + sred[5] + sred[6] + sred[7];
        float sumR2 = sred[8] + sred[9] + sred[10] + sred[11];
        const float inv = 1.f / ((float)NN * (float)NN);
        float mu  = 2.f * sumM * inv;
        float ex2 = (sumQ + 3.f * (float)NN * sumR2) * inv;
        stat[0] = mu;
        stat[1] = rsqrtf(ex2 - mu * mu + 1e-5f);
    }
    __syncthreads();
    const float mu = stat[0], rstd = stat[1];
#pragma unroll
    for (int r = 0; r < RG; ++r) {
        int i = i0 + r;
        size_t base = ((size_t)b * NN + i) * NN;
        float ri = rowsum[b * NN + i] * (1.f / NN);   // uniform, L1-hot
        out[base + t] = (out[base + t] + ri - mu) * rstd;
    }
}

extern "C" void kernel_launch(void* const* d_in, const int* in_sizes, int n_in,
                              void* d_out, int out_size, void* d_ws, size_t ws_size,
                              hipStream_t stream)
{
    const float* x     = (const float*)d_in[0];
    const float* W_out = (const float*)d_in[1];
    const float* b_out = (const float*)d_in[2];
    const float* W_cat = (const float*)d_in[3];
    const float* b_cat = (const float*)d_in[4];
    const float* W_f1  = (const float*)d_in[5];
    const float* b_f1  = (const float*)d_in[6];
    const float* W_f2  = (const float*)d_in[7];
    const float* b_f2  = (const float*)d_in[8];

    float* rowsum = (float*)d_ws;               // BB*NN
    float* rowsq  = rowsum + BB * NN;           // BB*NN
    float* outp   = (float*)d_out;

    pair_kernel<<<BB * BPB, 256, 0, stream>>>(
        x, W_out, b_out, W_cat, b_cat, W_f1, b_f1, W_f2, b_f2,
        rowsum, rowsq, outp);
    final_kernel<<<BB * BPB, 256, 0, stream>>>(rowsum, rowsq, outp);
}